// Round 1
// baseline (583.156 us; speedup 1.0000x reference)
//
#include <hip/hip_runtime.h>
#include <hip/hip_bf16.h>
#include <stdint.h>

// GraphTripleConv: B=32, O=4096, T=16384, D=H=DOUT=128
// out = [new_obj (B*O*128) | new_p (B*T*128)], f32
#define Bn 32
#define On 4096
#define Tn 16384
#define Dn 128

typedef short short8 __attribute__((ext_vector_type(8)));
typedef float f32x4 __attribute__((ext_vector_type(4)));

__device__ inline short f2bf(float f) {
  union { float f; uint32_t u; } v; v.f = f;
  uint32_t u = v.u;
  uint32_t r = u + 0x7fffu + ((u >> 16) & 1u);  // RNE
  return (short)(r >> 16);
}

// ---- weight prep: f32 [K][N] -> bf16 [N][K] (transposed so MFMA B-frag = 16B load)
// w1t: 128x384 ; w2t: 256x128 (only cols 128..383 of W2 -- new_s is dead code)
// w3t: 128x128 ; w4t: 128x128
__global__ void prep_weights(const float* __restrict__ W1, const float* __restrict__ W2,
                             const float* __restrict__ W3, const float* __restrict__ W4,
                             short* __restrict__ w1t, short* __restrict__ w2t,
                             short* __restrict__ w3t, short* __restrict__ w4t) {
  int i = blockIdx.x * 256 + threadIdx.x;
  if (i < 49152) {
    int n = i / 384, k = i % 384;
    w1t[i] = f2bf(W1[k * 128 + n]);
  } else if (i < 49152 + 32768) {
    int j = i - 49152;
    int n = j / 128, k = j % 128;
    w2t[j] = f2bf(W2[k * 384 + 128 + n]);
  } else if (i < 49152 + 32768 + 16384) {
    int j = i - 81920;
    int n = j / 128, k = j % 128;
    w3t[j] = f2bf(W3[k * 128 + n]);
  } else if (i < 114688) {
    int j = i - 98304;
    int n = j / 128, k = j % 128;
    w4t[j] = f2bf(W4[k * 128 + n]);
  }
}

// ---- edge MLP: gather [s|p|o] (384) -> GEMM1(K=384,N=128) -> GEMM2(K=128,N=256)
// cols 0..127 of GEMM2 = new_p (store), cols 128..255 = new_o (atomic scatter to pooled)
__global__ __launch_bounds__(256, 2) void edge_mlp(
    const float* __restrict__ obj, const float* __restrict__ pred,
    const int* __restrict__ edges,
    const short* __restrict__ w1t, const short* __restrict__ w2t,
    const float* __restrict__ b1, const float* __restrict__ g1, const float* __restrict__ be1,
    const float* __restrict__ b2, const float* __restrict__ g2, const float* __restrict__ be2,
    float* __restrict__ out_p, float* __restrict__ pooled, float* __restrict__ counts)
{
  __shared__ short xs[64][392];    // 64 rows x 384 bf16, pad->392 (2-way bank alias: free)
  __shared__ short h1s[64][136];   // h1 tile, pad->136
  __shared__ int olds[64];

  const float invs = 1.0f / sqrtf(1.001f);   // g / sqrt(1+EPS)
  int blk = blockIdx.x;
  int b = blk >> 8;                 // 256 blocks per batch (16384/64)
  int t0 = (blk & 255) << 6;
  int tid = threadIdx.x;

  // ---- stage gathered input rows as bf16 into LDS (4 threads per row, 96 elems each)
  {
    int r = tid >> 2, seg = tid & 3;
    int t = t0 + r;
    int e = (b * Tn + t) * 2;
    int sidx = edges[e], oidx = edges[e + 1];
    if (seg == 0) { olds[r] = oidx; atomicAdd(&counts[b * On + oidx], 1.0f); }
    const float* srow = obj + (size_t)(b * On + sidx) * Dn;
    const float* prow = pred + (size_t)(b * Tn + t) * Dn;
    const float* orow = obj + (size_t)(b * On + oidx) * Dn;
#pragma unroll
    for (int i = 0; i < 12; i++) {
      int k = seg * 96 + i * 8;     // 8-groups never straddle the 128-boundaries
      const float* src = (k < 128) ? (srow + k) : (k < 256 ? prow + (k - 128) : orow + (k - 256));
      float4 v0 = *(const float4*)(src);
      float4 v1 = *(const float4*)(src + 4);
      short8 pk;
      pk[0]=f2bf(v0.x); pk[1]=f2bf(v0.y); pk[2]=f2bf(v0.z); pk[3]=f2bf(v0.w);
      pk[4]=f2bf(v1.x); pk[5]=f2bf(v1.y); pk[6]=f2bf(v1.z); pk[7]=f2bf(v1.w);
      *(short8*)&xs[r][k] = pk;
    }
  }
  __syncthreads();

  int wave = tid >> 6, lane = tid & 63;
  int l15 = lane & 15, l4 = lane >> 4;

  // ---- GEMM1: 64x384 @ 384x128 ; wave owns 32 output cols
  f32x4 acc1[4][2] = {};
  int n0 = wave * 32;
  for (int kk = 0; kk < 12; kk++) {
    int k0 = kk * 32;
    short8 a[4], bb[2];
#pragma unroll
    for (int m = 0; m < 4; m++) a[m] = *(short8*)&xs[m * 16 + l15][k0 + 8 * l4];
#pragma unroll
    for (int n = 0; n < 2; n++) bb[n] = *(const short8*)&w1t[(n0 + n * 16 + l15) * 384 + k0 + 8 * l4];
#pragma unroll
    for (int m = 0; m < 4; m++)
#pragma unroll
      for (int n = 0; n < 2; n++)
        acc1[m][n] = __builtin_amdgcn_mfma_f32_16x16x32_bf16(a[m], bb[n], acc1[m][n], 0, 0, 0);
  }
  // epilogue: affine + relu -> bf16 h1 in LDS  (C layout: col=lane&15, row=(lane>>4)*4+reg)
#pragma unroll
  for (int n = 0; n < 2; n++) {
    int col = n0 + n * 16 + l15;
    float gs = g1[col] * invs;
    float add = b1[col] * gs + be1[col];
#pragma unroll
    for (int m = 0; m < 4; m++)
#pragma unroll
      for (int rr = 0; rr < 4; rr++) {
        float v = fmaxf(acc1[m][n][rr] * gs + add, 0.0f);
        h1s[m * 16 + l4 * 4 + rr][col] = f2bf(v);
      }
  }
  __syncthreads();

  // ---- GEMM2: 64x128 @ 128x256 (live cols only); wave owns 64 output cols
  f32x4 acc2[4][4] = {};
  int n0b = wave * 64;
  for (int kk = 0; kk < 4; kk++) {
    int k0 = kk * 32;
    short8 a[4], bb[4];
#pragma unroll
    for (int m = 0; m < 4; m++) a[m] = *(short8*)&h1s[m * 16 + l15][k0 + 8 * l4];
#pragma unroll
    for (int n = 0; n < 4; n++) bb[n] = *(const short8*)&w2t[(n0b + n * 16 + l15) * 128 + k0 + 8 * l4];
#pragma unroll
    for (int m = 0; m < 4; m++)
#pragma unroll
      for (int n = 0; n < 4; n++)
        acc2[m][n] = __builtin_amdgcn_mfma_f32_16x16x32_bf16(a[m], bb[n], acc2[m][n], 0, 0, 0);
  }
  // epilogue: waves 0,1 -> new_p stores ; waves 2,3 -> pooled atomics (wave-uniform branch)
#pragma unroll
  for (int n = 0; n < 4; n++) {
    int colp = n0b + n * 16 + l15;   // 0..255
    int c2 = 128 + colp;             // original W2 output column
    float gs = g2[c2] * invs;
    float add = b2[c2] * gs + be2[c2];
#pragma unroll
    for (int m = 0; m < 4; m++)
#pragma unroll
      for (int rr = 0; rr < 4; rr++) {
        int row = m * 16 + l4 * 4 + rr;
        float v = fmaxf(acc2[m][n][rr] * gs + add, 0.0f);
        if (colp < 128) {
          out_p[(size_t)(b * Tn + t0 + row) * 128 + colp] = v;
        } else {
          atomicAdd(&pooled[(size_t)(b * On + olds[row]) * 128 + (colp - 128)], v);
        }
      }
  }
}

// ---- object MLP: pooled/count -> GEMM3(128x128) -> GEMM4(128x128), in-place on d_out
__global__ __launch_bounds__(256) void obj_mlp(
    float* __restrict__ io, const float* __restrict__ counts,
    const short* __restrict__ w3t, const short* __restrict__ w4t,
    const float* __restrict__ b3, const float* __restrict__ g3, const float* __restrict__ be3,
    const float* __restrict__ b4, const float* __restrict__ g4, const float* __restrict__ be4)
{
  __shared__ short xs[64][136];
  __shared__ short hs[64][136];
  const float invs = 1.0f / sqrtf(1.001f);
  int row0 = blockIdx.x * 64;
  int tid = threadIdx.x;
  {
    int r = tid >> 2, seg = tid & 3;
    float c = counts[row0 + r];
    float ic = 1.0f / fmaxf(c, 1.0f);
    const float* src = io + (size_t)(row0 + r) * 128 + seg * 32;
#pragma unroll
    for (int i = 0; i < 4; i++) {
      float4 v0 = *(const float4*)(src + i * 8);
      float4 v1 = *(const float4*)(src + i * 8 + 4);
      short8 pk;
      pk[0]=f2bf(v0.x*ic); pk[1]=f2bf(v0.y*ic); pk[2]=f2bf(v0.z*ic); pk[3]=f2bf(v0.w*ic);
      pk[4]=f2bf(v1.x*ic); pk[5]=f2bf(v1.y*ic); pk[6]=f2bf(v1.z*ic); pk[7]=f2bf(v1.w*ic);
      *(short8*)&xs[r][seg * 32 + i * 8] = pk;
    }
  }
  __syncthreads();

  int wave = tid >> 6, lane = tid & 63;
  int l15 = lane & 15, l4 = lane >> 4;
  int n0 = wave * 32;

  f32x4 acc[4][2] = {};
  for (int kk = 0; kk < 4; kk++) {
    int k0 = kk * 32;
    short8 a[4], bb[2];
#pragma unroll
    for (int m = 0; m < 4; m++) a[m] = *(short8*)&xs[m * 16 + l15][k0 + 8 * l4];
#pragma unroll
    for (int n = 0; n < 2; n++) bb[n] = *(const short8*)&w3t[(n0 + n * 16 + l15) * 128 + k0 + 8 * l4];
#pragma unroll
    for (int m = 0; m < 4; m++)
#pragma unroll
      for (int n = 0; n < 2; n++)
        acc[m][n] = __builtin_amdgcn_mfma_f32_16x16x32_bf16(a[m], bb[n], acc[m][n], 0, 0, 0);
  }
#pragma unroll
  for (int n = 0; n < 2; n++) {
    int col = n0 + n * 16 + l15;
    float gs = g3[col] * invs;
    float add = b3[col] * gs + be3[col];
#pragma unroll
    for (int m = 0; m < 4; m++)
#pragma unroll
      for (int rr = 0; rr < 4; rr++) {
        float v = fmaxf(acc[m][n][rr] * gs + add, 0.0f);
        hs[m * 16 + l4 * 4 + rr][col] = f2bf(v);
      }
  }
  __syncthreads();

  f32x4 acc2[4][2] = {};
  for (int kk = 0; kk < 4; kk++) {
    int k0 = kk * 32;
    short8 a[4], bb[2];
#pragma unroll
    for (int m = 0; m < 4; m++) a[m] = *(short8*)&hs[m * 16 + l15][k0 + 8 * l4];
#pragma unroll
    for (int n = 0; n < 2; n++) bb[n] = *(const short8*)&w4t[(n0 + n * 16 + l15) * 128 + k0 + 8 * l4];
#pragma unroll
    for (int m = 0; m < 4; m++)
#pragma unroll
      for (int n = 0; n < 2; n++)
        acc2[m][n] = __builtin_amdgcn_mfma_f32_16x16x32_bf16(a[m], bb[n], acc2[m][n], 0, 0, 0);
  }
#pragma unroll
  for (int n = 0; n < 2; n++) {
    int col = n0 + n * 16 + l15;
    float gs = g4[col] * invs;
    float add = b4[col] * gs + be4[col];
#pragma unroll
    for (int m = 0; m < 4; m++)
#pragma unroll
      for (int rr = 0; rr < 4; rr++) {
        int row = m * 16 + l4 * 4 + rr;
        float v = fmaxf(acc2[m][n][rr] * gs + add, 0.0f);
        io[(size_t)(row0 + row) * 128 + col] = v;
      }
  }
}

extern "C" void kernel_launch(void* const* d_in, const int* in_sizes, int n_in,
                              void* d_out, int out_size, void* d_ws, size_t ws_size,
                              hipStream_t stream) {
  const float* obj  = (const float*)d_in[0];
  const float* pred = (const float*)d_in[1];
  const int*   edges= (const int*)d_in[2];
  const float* W1 = (const float*)d_in[3];
  const float* b1 = (const float*)d_in[4];
  const float* g1 = (const float*)d_in[5];
  const float* be1= (const float*)d_in[6];
  const float* W2 = (const float*)d_in[7];
  const float* b2 = (const float*)d_in[8];
  const float* g2 = (const float*)d_in[9];
  const float* be2= (const float*)d_in[10];
  const float* W3 = (const float*)d_in[11];
  const float* b3 = (const float*)d_in[12];
  const float* g3 = (const float*)d_in[13];
  const float* be3= (const float*)d_in[14];
  const float* W4 = (const float*)d_in[15];
  const float* b4 = (const float*)d_in[16];
  const float* g4 = (const float*)d_in[17];
  const float* be4= (const float*)d_in[18];

  float* out_obj = (float*)d_out;                           // B*O*128, also pooled accum
  float* out_p   = (float*)d_out + (size_t)Bn * On * 128;   // B*T*128

  char* ws = (char*)d_ws;
  float* counts = (float*)ws;                               // B*O floats = 512KB
  short* w1t = (short*)(ws + 524288);
  short* w2t = (short*)(ws + 524288 + 98304);
  short* w3t = (short*)(ws + 524288 + 98304 + 65536);
  short* w4t = (short*)(ws + 524288 + 98304 + 65536 + 32768);

  // zero accumulators every call (harness does not re-poison between replays)
  hipMemsetAsync(counts, 0, (size_t)Bn * On * 4, stream);
  hipMemsetAsync(out_obj, 0, (size_t)Bn * On * 128 * 4, stream);

  prep_weights<<<448, 256, 0, stream>>>(W1, W2, W3, W4, w1t, w2t, w3t, w4t);
  edge_mlp<<<Bn * (Tn / 64), 256, 0, stream>>>(obj, pred, edges, w1t, w2t,
      b1, g1, be1, b2, g2, be2, out_p, out_obj, counts);
  obj_mlp<<<(Bn * On) / 64, 256, 0, stream>>>(out_obj, counts, w3t, w4t,
      b3, g3, be3, b4, g4, be4);
}